// Round 17
// baseline (62.696 us; speedup 1.0000x reference)
//
#include <hip/hip_runtime.h>
#include <hip/hip_bf16.h>
#include <stdint.h>

// RNDiscriminator: B=64, d^2=64 positions, 26 features, g: 52->256->256, f: 256->1
// h1[i,j] = relu(u'[j] + v[i]); dominant cost sum_ij relu(h1 @ W2 + b2) = 34.4 GF bf16.
//
// R17: MAX OCCUPANCY -- 1024-thread blocks (16 waves = 4 waves/SIMD, the VGPR
// ceiling at 128 regs). Six schedule variants at 2-3 waves/SIMD all plateaued
// at k3~38us with MfmaUtil ~32%; this attacks latency-hiding via TLP.
// Wave tile 32x32: Bf[8][2]=64 VGPR, acc[2][2]=16, u packed-bf16 8 -> ~114 regs.
// h1 frag-major LDS + per-frag XOR (conflict-free write AND read). dbuf, 2
// barriers/pair. vs reads bank-swizzled.

typedef float f32x4 __attribute__((ext_vector_type(4)));
typedef float f32x2 __attribute__((ext_vector_type(2)));
typedef short short8 __attribute__((ext_vector_type(8)));
typedef int   int4v  __attribute__((ext_vector_type(4)));

__device__ __forceinline__ uint32_t cvt_pk_bf16(float lo, float hi) {
    uint32_t r;
    asm("v_cvt_pk_bf16_f32 %0, %1, %2" : "=v"(r) : "v"(lo), "v"(hi));
    return r;
}
__device__ __forceinline__ f32x2 relu2(f32x2 a) {
    f32x2 z = (f32x2){0.f, 0.f};
    return __builtin_elementwise_max(a, z);
}
// h1 pair from packed-bf16 u + f32 v: relu(u+v) -> packed bf16
__device__ __forceinline__ uint32_t fuse2(uint32_t up, float vlo, float vhi) {
    f32x2 uu;
    uu.x = __uint_as_float(up << 16);
    uu.y = __uint_as_float(up & 0xFFFF0000u);
    f32x2 r = relu2(uu + (f32x2){vlo, vhi});
    return cvt_pk_bf16(r.x, r.y);
}

// K12: blocks 0..255: fused conv(8x8/s8)+relu+coords -> u,v rows.
//      blocks 256..287: pre-fragment W2 (bf16, fragment-major, 16x16 layout).
__global__ void k12_front(const float* __restrict__ img, const float* __restrict__ cw,
                          const float* __restrict__ cb, const float* __restrict__ w1,
                          const float* __restrict__ b1, const float* __restrict__ w2,
                          float* __restrict__ u, float* __restrict__ v,
                          short* __restrict__ w2f) {
    int g = blockIdx.x;
    int t = threadIdx.x;
    if (g >= 256) {
        int fi = (g - 256) * 4 + (t >> 6);
        int l = t & 63;
        int ks = fi >> 4, ni2 = fi & 15;
        int n  = ni2 * 16 + (l & 15);
        int k0 = ks * 32 + (l >> 4) * 8;
        float f[8];
        #pragma unroll
        for (int e = 0; e < 8; ++e) f[e] = w2[(k0 + e) * 256 + n];
        union { short8 s; uint32_t w[4]; } A;
        A.w[0] = cvt_pk_bf16(f[0], f[1]);
        A.w[1] = cvt_pk_bf16(f[2], f[3]);
        A.w[2] = cvt_pk_bf16(f[4], f[5]);
        A.w[3] = cvt_pk_bf16(f[6], f[7]);
        *(short8*)(w2f + (fi * 64 + l) * 8) = A.s;
        return;
    }
    __shared__ float xs[16][26];
    int b = g >> 2, q = g & 3, p0 = q * 16;

    for (int idx = t; idx < 416; idx += 256) {
        int pl = idx / 26;
        int ch = idx - pl * 26;
        int pos = p0 + pl;
        int r = pos >> 3, c = pos & 7;
        float val;
        if (ch < 24) {
            float s = cb[ch];
            #pragma unroll
            for (int ci = 0; ci < 3; ++ci)
                #pragma unroll
                for (int kr = 0; kr < 8; ++kr) {
                    const float* ip = img + ((b * 3 + ci) * 64 + r * 8 + kr) * 64 + c * 8;
                    const float* wp = cw + ((ch * 3 + ci) * 8 + kr) * 8;
                    #pragma unroll
                    for (int kc = 0; kc < 8; ++kc) s += ip[kc] * wp[kc];
                }
            val = fmaxf(s, 0.f);
        } else if (ch == 24) {
            val = -1.f + (2.f / 7.f) * (float)c;
        } else {
            val = -1.f + (2.f / 7.f) * (float)r;
        }
        xs[pl][ch] = val;
    }
    __syncthreads();

    int c = t;
    float bc = b1[c];
    float su[16], sv[16];
    #pragma unroll
    for (int r = 0; r < 16; ++r) { su[r] = bc; sv[r] = 0.f; }
    #pragma unroll 2
    for (int k = 0; k < 26; ++k) {
        float wu = w1[k * 256 + c];
        float wv2 = w1[(26 + k) * 256 + c];
        #pragma unroll
        for (int r = 0; r < 16; ++r) {
            float xv = xs[r][k];
            su[r] += xv * wu;
            sv[r] += xv * wv2;
        }
    }
    #pragma unroll
    for (int r = 0; r < 16; ++r) {
        int bj = b * 64 + p0 + r;
        u[bj * 256 + c] = su[r];
        v[bj * 256 + c] = sv[r];
    }
}

// vs slot swizzle: float4 slot s (0..63) -> s' spreads bank-quads
__device__ __forceinline__ int vslot(int s) {
    return (((s & 15) << 2) | (s >> 4)) << 4;   // byte offset within 1KB row
}

__global__ __launch_bounds__(1024, 4) void k3_pairs(
        const float* __restrict__ u, const float* __restrict__ v,
        const short* __restrict__ w2f, const float* __restrict__ b2,
        float* __restrict__ part) {
    __shared__ short h1s[2][64 * 256];   // 2 x 32 KB dbuf, frag-major + XOR
    __shared__ float vs[16 * 256];       // 16 KB, slot-swizzled
    int t = threadIdx.x;
    int lane = t & 63, wv = t >> 6;      // wv 0..15
    int lr = lane & 15, lg = lane >> 4;
    int blk = blockIdx.x;                // 0..255
    int b = blk & 63, i0 = (blk >> 6) * 16;
    int wr = wv & 1, wc = wv >> 1;       // rows wr*32..+32, cols wc*32..+32

    // ---- stage the 16 v rows once, slot-swizzled (1 float4/thread) ----
    {
        int q = t >> 6, s = t & 63;
        const float* vr = v + (b * 64 + i0 + q) * 256 + s * 4;
        *(float4*)((char*)vs + q * 1024 + vslot(s)) = *(const float4*)vr;
    }

    // ---- resident B fragments: cols wc*32 + cg*16 (static indices) ----
    short8 Bf[8][2];
    #pragma unroll
    for (int ks = 0; ks < 8; ++ks)
        #pragma unroll
        for (int cg = 0; cg < 2; ++cg)
            Bf[ks][cg] = *(const short8*)(w2f + ((ks * 16 + wc * 2 + cg) * 64 + lane) * 8);

    float bias[2];
    #pragma unroll
    for (int cg = 0; cg < 2; ++cg) bias[cg] = b2[wc * 32 + cg * 16 + lr];

    // ---- u residency: thread (row = t>>4, col16 = t&15) holds 16 bf16 ----
    int row = t >> 4, col16 = t & 15;
    uint32_t upk[8];
    {
        const float* up = u + (b * 64 + row) * 256 + col16 * 16;
        #pragma unroll
        for (int h = 0; h < 2; ++h) {
            f32x4 x0 = *(const f32x4*)(up + h * 8);
            f32x4 x1 = *(const f32x4*)(up + h * 8 + 4);
            upk[h * 4 + 0] = cvt_pk_bf16(x0.x, x0.y);
            upk[h * 4 + 1] = cvt_pk_bf16(x0.z, x0.w);
            upk[h * 4 + 2] = cvt_pk_bf16(x1.x, x1.y);
            upk[h * 4 + 3] = cvt_pk_bf16(x1.z, x1.w);
        }
    }
    // write addrs (pair-invariant): octet o = col16*2+h, ks=o>>2, qk=o&3
    // frag f = (row>>4)*8 + ks; lane_a = (row&15) + qk*16; XOR by ks
    int wa[2];
    #pragma unroll
    for (int h = 0; h < 2; ++h) {
        int o = col16 * 2 + h;
        int ks = o >> 2, qk = o & 3;
        int f = (row >> 4) * 8 + ks;
        int la = (row & 15) + qk * 16;
        wa[h] = f * 1024 + ((la ^ ks) << 4);
    }
    // vs read offsets (pair-invariant): 4 float4 slots s = col16*4+j
    int rs[4];
    #pragma unroll
    for (int j = 0; j < 4; ++j) rs[j] = vslot(col16 * 4 + j);

    // ---- STAGE macro: one pair's h1 rows (this thread's 16 elems) ----
    #define STAGE(Q, BUF)                                                  \
    {                                                                      \
        const char* vq = (const char*)vs + (Q) * 1024;                     \
        f32x4 va = *(const f32x4*)(vq + rs[0]);                            \
        f32x4 vb = *(const f32x4*)(vq + rs[1]);                            \
        f32x4 vc = *(const f32x4*)(vq + rs[2]);                            \
        f32x4 vd = *(const f32x4*)(vq + rs[3]);                            \
        int4v d0, d1;                                                      \
        d0.x = (int)fuse2(upk[0], va.x, va.y);                             \
        d0.y = (int)fuse2(upk[1], va.z, va.w);                             \
        d0.z = (int)fuse2(upk[2], vb.x, vb.y);                             \
        d0.w = (int)fuse2(upk[3], vb.z, vb.w);                             \
        d1.x = (int)fuse2(upk[4], vc.x, vc.y);                             \
        d1.y = (int)fuse2(upk[5], vc.z, vc.w);                             \
        d1.z = (int)fuse2(upk[6], vd.x, vd.y);                             \
        d1.w = (int)fuse2(upk[7], vd.z, vd.w);                             \
        *(int4v*)((char*)(BUF) + wa[0]) = d0;                              \
        *(int4v*)((char*)(BUF) + wa[1]) = d1;                              \
    }

    __syncthreads();            // vs ready
    STAGE(0, h1s[0])
    __syncthreads();            // buf0 ready

    // consumer read base: frag f = (wr*2+mi)*8 + ks, addr = f*1024 + ((lane^ks)<<4)
    float csum[2] = {0.f, 0.f};

    #pragma unroll 1
    for (int q = 0; q < 16; ++q) {
        const char* hb = (const char*)h1s[q & 1];
        int mbase = wr * 2 * 8192;     // (wr*2)*8*1024

        f32x4 acc[2][2];
        #pragma unroll
        for (int mi = 0; mi < 2; ++mi)
            #pragma unroll
            for (int cg = 0; cg < 2; ++cg) acc[mi][cg] = (f32x4){0.f, 0.f, 0.f, 0.f};

        #pragma unroll
        for (int ks = 0; ks < 8; ++ks) {
            int xo = ((lane ^ ks) << 4) + ks * 1024;
            short8 a0 = *(const short8*)(hb + mbase + xo);
            short8 a1 = *(const short8*)(hb + mbase + 8192 + xo);
            acc[0][0] = __builtin_amdgcn_mfma_f32_16x16x32_bf16(a0, Bf[ks][0], acc[0][0], 0, 0, 0);
            acc[1][0] = __builtin_amdgcn_mfma_f32_16x16x32_bf16(a1, Bf[ks][0], acc[1][0], 0, 0, 0);
            acc[0][1] = __builtin_amdgcn_mfma_f32_16x16x32_bf16(a0, Bf[ks][1], acc[0][1], 0, 0, 0);
            acc[1][1] = __builtin_amdgcn_mfma_f32_16x16x32_bf16(a1, Bf[ks][1], acc[1][1], 0, 0, 0);
        }
        __syncthreads();        // everyone done reading buf[q&1]

        if (q < 15) STAGE(q + 1, h1s[(q + 1) & 1])

        // epilogue: relu(C + b2) partial column-sum
        #pragma unroll
        for (int cg = 0; cg < 2; ++cg) {
            float s = csum[cg];
            #pragma unroll
            for (int mi = 0; mi < 2; ++mi)
                #pragma unroll
                for (int r = 0; r < 4; ++r)
                    s += fmaxf(acc[mi][cg][r] + bias[cg], 0.f);
            csum[cg] = s;
        }
        __syncthreads();        // buf[(q+1)&1] staged for all
    }
    #undef STAGE

    // flush: reduce over lg groups; lanes 0-15 store this wave's 32-col partial
    #pragma unroll
    for (int cg = 0; cg < 2; ++cg) {
        float s = csum[cg];
        s += __shfl_xor(s, 16);
        s += __shfl_xor(s, 32);
        if (lane < 16) part[(blk * 16 + wv) * 32 + cg * 16 + lr] = s;
    }
}

// K5: pooled[b][c] = sum over 4 i-quarters x 2 row-halves; then f-head.
__global__ void k5_head(const float* __restrict__ part, const float* __restrict__ fw1,
                        const float* __restrict__ fb1, const float* __restrict__ fw2,
                        const float* __restrict__ fb2, float* __restrict__ out) {
    __shared__ float P[256];
    __shared__ float wsum[4];
    int b = blockIdx.x, t = threadIdx.x;
    int wc = t >> 5, cl = t & 31;
    float s0 = 0.f;
    #pragma unroll
    for (int g = 0; g < 4; ++g) {
        const float* p = part + ((b + 64 * g) * 16 + wc * 2) * 32 + cl;
        s0 += p[0] + p[32];     // wr = 0, 1
    }
    P[t] = s0;
    __syncthreads();
    float a0 = 0.f, a1 = 0.f, a2 = 0.f, a3 = 0.f;
    for (int k = 0; k < 64; ++k) {
        a0 += P[k]       * fw1[k * 256 + t];
        a1 += P[k + 64]  * fw1[(k + 64) * 256 + t];
        a2 += P[k + 128] * fw1[(k + 128) * 256 + t];
        a3 += P[k + 192] * fw1[(k + 192) * 256 + t];
    }
    float h = fmaxf(fb1[t] + a0 + a1 + a2 + a3, 0.f);
    float p = h * fw2[t];
    #pragma unroll
    for (int off = 32; off >= 1; off >>= 1) p += __shfl_xor(p, off);
    if ((t & 63) == 0) wsum[t >> 6] = p;
    __syncthreads();
    if (t == 0) out[b] = wsum[0] + wsum[1] + wsum[2] + wsum[3] + fb2[0];
}

extern "C" void kernel_launch(void* const* d_in, const int* in_sizes, int n_in,
                              void* d_out, int out_size, void* d_ws, size_t ws_size,
                              hipStream_t stream) {
    const float* image  = (const float*)d_in[0];
    const float* conv_w = (const float*)d_in[1];
    const float* conv_b = (const float*)d_in[2];
    const float* g_w1   = (const float*)d_in[3];
    const float* g_b1   = (const float*)d_in[4];
    const float* g_w2   = (const float*)d_in[5];
    const float* g_b2   = (const float*)d_in[6];
    const float* f_w1   = (const float*)d_in[7];
    const float* f_b1   = (const float*)d_in[8];
    const float* f_w2   = (const float*)d_in[9];
    const float* f_b2   = (const float*)d_in[10];
    float* out = (float*)d_out;

    char* ws = (char*)d_ws;
    float* u    = (float*)(ws + 0);          // 64*64*256*4 = 4 MB
    float* v    = (float*)(ws + 4194304);    // 4 MB
    short* w2f  = (short*)(ws + 8388608);    // 128 KB
    float* part = (float*)(ws + 8519680);    // 256*16*32*4 = 512 KB

    k12_front<<<288, 256, 0, stream>>>(image, conv_w, conv_b, g_w1, g_b1, g_w2,
                                       u, v, w2f);
    k3_pairs<<<256, 1024, 0, stream>>>(u, v, w2f, g_b2, part);
    k5_head<<<64, 256, 0, stream>>>(part, f_w1, f_b1, f_w2, f_b2, out);
}